// Round 2
// baseline (10900.865 us; speedup 1.0000x reference)
//
#include <hip/hip_runtime.h>
#include <math.h>

#define EMB   1024
#define HID   1024
#define BATCH   64
#define SEQ    512

#define NBG    16   // batch groups
#define BTILE   4   // batches per group (NBG*BTILE = 64)
#define NJT    16   // j-tiles (producers per batch group)
#define JTILE  64   // j per tile (NJT*JTILE = 1024)

// ---------------------------------------------------------------------------
// Kernel A: x_proj GEMM.  out[(s*64+b)*1024 + n] = sum_k embeds[b][s][k]*W_ih[n][k]
//                                                  + b_ih[n] + b_hh[n]
// (unchanged from round 1 — fp32 tiled GEMM, 64x64 tile, 4x4 micro-tile)
// ---------------------------------------------------------------------------
__global__ __launch_bounds__(256) void xproj_gemm(
    const float* __restrict__ A,
    const float* __restrict__ W,
    const float* __restrict__ b_ih,
    const float* __restrict__ b_hh,
    float* __restrict__ out)
{
    __shared__ float As[16][68];
    __shared__ float Ws[16][68];

    const int tid = threadIdx.x;
    const int tx  = tid & 15;
    const int ty  = tid >> 4;
    const int m0  = blockIdx.y * 64;
    const int n0  = blockIdx.x * 64;
    const int lrow = tid >> 2;
    const int lk   = (tid & 3) * 4;

    float acc[4][4] = {};

    for (int kt = 0; kt < EMB; kt += 16) {
        float4 av = *(const float4*)&A[(size_t)(m0 + lrow) * EMB + kt + lk];
        float4 wv = *(const float4*)&W[(size_t)(n0 + lrow) * EMB + kt + lk];
        As[lk + 0][lrow] = av.x; As[lk + 1][lrow] = av.y;
        As[lk + 2][lrow] = av.z; As[lk + 3][lrow] = av.w;
        Ws[lk + 0][lrow] = wv.x; Ws[lk + 1][lrow] = wv.y;
        Ws[lk + 2][lrow] = wv.z; Ws[lk + 3][lrow] = wv.w;
        __syncthreads();
        #pragma unroll
        for (int kk = 0; kk < 16; ++kk) {
            float4 a = *(const float4*)&As[kk][ty * 4];
            float4 w = *(const float4*)&Ws[kk][tx * 4];
            acc[0][0] += a.x * w.x; acc[0][1] += a.x * w.y;
            acc[0][2] += a.x * w.z; acc[0][3] += a.x * w.w;
            acc[1][0] += a.y * w.x; acc[1][1] += a.y * w.y;
            acc[1][2] += a.y * w.z; acc[1][3] += a.y * w.w;
            acc[2][0] += a.z * w.x; acc[2][1] += a.z * w.y;
            acc[2][2] += a.z * w.z; acc[2][3] += a.z * w.w;
            acc[3][0] += a.w * w.x; acc[3][1] += a.w * w.y;
            acc[3][2] += a.w * w.z; acc[3][3] += a.w * w.w;
        }
        __syncthreads();
    }

    const int n = n0 + tx * 4;
    float bias[4];
    #pragma unroll
    for (int j = 0; j < 4; ++j) bias[j] = b_ih[n + j] + b_hh[n + j];

    #pragma unroll
    for (int i = 0; i < 4; ++i) {
        const int m = m0 + ty * 4 + i;
        const int b = m >> 9;
        const int s = m & 511;
        float4 o;
        o.x = acc[i][0] + bias[0];
        o.y = acc[i][1] + bias[1];
        o.z = acc[i][2] + bias[2];
        o.w = acc[i][3] + bias[3];
        *(float4*)&out[((size_t)(s * 64 + b) << 10) + n] = o;
    }
}

// ---------------------------------------------------------------------------
// 16-lane sum reduction on the VALU via DPP (no DS-pipe pressure).
// Lanes are grouped [jp*16, jp*16+16); after this all 16 lanes hold the sum.
// ---------------------------------------------------------------------------
__device__ __forceinline__ float red16(float x) {
    int xi, yi;
    xi = __builtin_bit_cast(int, x);
    yi = __builtin_amdgcn_update_dpp(0, xi, 0xB1, 0xF, 0xF, true);  // quad_perm xor1
    x += __builtin_bit_cast(float, yi);
    xi = __builtin_bit_cast(int, x);
    yi = __builtin_amdgcn_update_dpp(0, xi, 0x4E, 0xF, 0xF, true);  // quad_perm xor2
    x += __builtin_bit_cast(float, yi);
    xi = __builtin_bit_cast(int, x);
    yi = __builtin_amdgcn_update_dpp(0, xi, 0x124, 0xF, 0xF, true); // row_ror:4
    x += __builtin_bit_cast(float, yi);
    xi = __builtin_bit_cast(int, x);
    yi = __builtin_amdgcn_update_dpp(0, xi, 0x128, 0xF, 0xF, true); // row_ror:8
    x += __builtin_bit_cast(float, yi);
    return x;
}

// ---------------------------------------------------------------------------
// Persistent recurrence kernel: all 512 timesteps in one launch.
// Grid (NJT, NBG) = 256 WGs x 512 threads; each WG owns a 4-batch x 64-j tile.
// W_hh slice lives in VGPRs (128 floats/lane: 2 j-rows x 64-k chunk).
// Per step: stage the 4x1024 h-slice in LDS, 512 FMA/lane, DPP K-reduce,
// tanh+write, flag release. b-groups sync independently via flags in d_ws.
// ---------------------------------------------------------------------------
__global__ __launch_bounds__(512, 2) void rnn_persist(
    const float* __restrict__ Whh,    // HID x HID row-major
    float* __restrict__ out,          // (S, B, HID); xp in, h out (in place)
    int* __restrict__ flags)          // NBG x SEQ counters, pre-zeroed
{
    const int tid  = threadIdx.x;
    const int wave = tid >> 6;
    const int lane = tid & 63;
    const int c    = lane & 15;        // K-chunk index (Kc = 64)
    const int jp   = (lane >> 4) & 3;  // j-pair within wave
    const int jt   = blockIdx.x;
    const int bg   = blockIdx.y;
    const int jbase = jt * JTILE + wave * 8 + jp * 2;
    const int k0    = c * 64;

    // --- W_hh -> registers (persistent across all steps) ---
    float4 wr0[16], wr1[16];
    #pragma unroll
    for (int kq = 0; kq < 16; ++kq) {
        wr0[kq] = *(const float4*)&Whh[(size_t)jbase * HID + k0 + kq * 4];
        wr1[kq] = *(const float4*)&Whh[(size_t)(jbase + 1) * HID + k0 + kq * 4];
    }

    // h slice: [b][chunk c][64 floats], chunk stride 17 float4 (conflict-free)
    __shared__ float4 hs[BTILE * 272];

    int* flagrow = flags + bg * SEQ;

    // this lane's output slot (valid when c < 8): b = c>>1, j = jbase + (c&1)
    const int ob = c >> 1;
    const size_t oaddr = (size_t)(bg * BTILE + ob) * HID + (jbase + (c & 1));

    // --- t = 0: h0 = tanh(xp) ---
    if (c < 8) {
        out[oaddr] = tanhf(out[oaddr]);
    }
    __syncthreads();
    if (tid == 0) {
        __builtin_amdgcn_fence(__ATOMIC_RELEASE, "agent");
        __hip_atomic_fetch_add(&flagrow[0], 1, __ATOMIC_RELAXED,
                               __HIP_MEMORY_SCOPE_AGENT);
    }

    // --- t = 1 .. SEQ-1 ---
    for (int t = 1; t < SEQ; ++t) {
        float* cur        = out + (size_t)t * (BATCH * HID);
        const float* prev = cur - (BATCH * HID);

        // prefetch xp (GEMM output; stable, no sync needed)
        float xp = 0.f;
        if (c < 8) xp = cur[oaddr];

        // wait for all 16 producers of h(t-1) for this batch group
        if (tid == 0) {
            while (__hip_atomic_load(&flagrow[t - 1], __ATOMIC_RELAXED,
                                     __HIP_MEMORY_SCOPE_AGENT) < NJT)
                __builtin_amdgcn_s_sleep(2);
        }
        __syncthreads();
        __builtin_amdgcn_fence(__ATOMIC_ACQUIRE, "agent");

        // stage h(t-1) slice: 4 rows x 1024 floats = 1024 float4
        #pragma unroll
        for (int q = 0; q < 2; ++q) {
            int f   = q * 512 + tid;       // 0..1023
            int b   = f >> 8;
            int idx = f & 255;
            int cc  = idx >> 4;
            int kq  = idx & 15;
            hs[b * 272 + cc * 17 + kq] =
                *(const float4*)&prev[(size_t)(bg * BTILE + b) * HID + cc * 64 + kq * 4];
        }
        __syncthreads();

        // compute: acc[b][jj] = sum over this lane's 64-k chunk
        float acc[4][2];
        #pragma unroll
        for (int b = 0; b < 4; ++b) {
            const float4* hb = &hs[b * 272 + c * 17];
            float a0 = 0.f, a1 = 0.f;
            #pragma unroll
            for (int kq = 0; kq < 16; ++kq) {
                float4 h4 = hb[kq];
                a0 += h4.x * wr0[kq].x; a0 += h4.y * wr0[kq].y;
                a0 += h4.z * wr0[kq].z; a0 += h4.w * wr0[kq].w;
                a1 += h4.x * wr1[kq].x; a1 += h4.y * wr1[kq].y;
                a1 += h4.z * wr1[kq].z; a1 += h4.w * wr1[kq].w;
            }
            acc[b][0] = a0; acc[b][1] = a1;
        }

        // K-reduce across the 16 lanes of each jp-group (VALU DPP tree)
        #pragma unroll
        for (int b = 0; b < 4; ++b) {
            acc[b][0] = red16(acc[b][0]);
            acc[b][1] = red16(acc[b][1]);
        }

        // lane c<8 writes output (b = c>>1, jj = c&1) — cndmask select chain
        float vb0 = (c & 1) ? acc[0][1] : acc[0][0];
        float vb1 = (c & 1) ? acc[1][1] : acc[1][0];
        float vb2 = (c & 1) ? acc[2][1] : acc[2][0];
        float vb3 = (c & 1) ? acc[3][1] : acc[3][0];
        float vlo = (c & 2) ? vb1 : vb0;
        float vhi = (c & 2) ? vb3 : vb2;
        float v   = (c & 4) ? vhi : vlo;
        if (c < 8) cur[oaddr] = tanhf(xp + v);

        __syncthreads();   // drains each wave's stores (vmcnt 0 before barrier)
        if (tid == 0) {
            __builtin_amdgcn_fence(__ATOMIC_RELEASE, "agent");
            __hip_atomic_fetch_add(&flagrow[t], 1, __ATOMIC_RELAXED,
                                   __HIP_MEMORY_SCOPE_AGENT);
        }
    }
}

// ---------------------------------------------------------------------------
extern "C" void kernel_launch(void* const* d_in, const int* in_sizes, int n_in,
                              void* d_out, int out_size, void* d_ws, size_t ws_size,
                              hipStream_t stream) {
    const float* embeds = (const float*)d_in[0];
    const float* W_ih   = (const float*)d_in[1];
    const float* W_hh   = (const float*)d_in[2];
    const float* b_ih   = (const float*)d_in[3];
    const float* b_hh   = (const float*)d_in[4];
    float* out = (float*)d_out;

    (void)in_sizes; (void)n_in; (void)out_size; (void)ws_size;

    // zero the producer flags (d_ws is NOT re-poisoned between replays)
    hipMemsetAsync(d_ws, 0, NBG * SEQ * sizeof(int), stream);

    // Phase 1: x_proj for all timesteps, written into d_out at [s][b][:]
    dim3 gA(HID / 64, (BATCH * SEQ) / 64);
    xproj_gemm<<<gA, 256, 0, stream>>>(embeds, W_ih, b_ih, b_hh, out);

    // Phase 2: persistent recurrence (one launch, flag-pipelined)
    dim3 gR(NJT, NBG);
    rnn_persist<<<gR, 512, 0, stream>>>(W_hh, out, (int*)d_ws);
}

// Round 4
// 3613.852 us; speedup vs baseline: 3.0164x; 3.0164x over previous
//
#include <hip/hip_runtime.h>
#include <math.h>

#define EMB   1024
#define HID   1024
#define BATCH   64
#define SEQ    512

#define NBG    16   // batch groups
#define BTILE   4   // batches per group (NBG*BTILE = 64)
#define NJT    16   // j-tiles (producers per batch group)
#define JTILE  64   // j per tile (NJT*JTILE = 1024)

// ---------------------------------------------------------------------------
// Kernel A: x_proj GEMM.  out[(s*64+b)*1024 + n] = sum_k embeds[b][s][k]*W_ih[n][k]
//                                                  + b_ih[n] + b_hh[n]
// ---------------------------------------------------------------------------
__global__ __launch_bounds__(256) void xproj_gemm(
    const float* __restrict__ A,
    const float* __restrict__ W,
    const float* __restrict__ b_ih,
    const float* __restrict__ b_hh,
    float* __restrict__ out)
{
    __shared__ float As[16][68];
    __shared__ float Ws[16][68];

    const int tid = threadIdx.x;
    const int tx  = tid & 15;
    const int ty  = tid >> 4;
    const int m0  = blockIdx.y * 64;
    const int n0  = blockIdx.x * 64;
    const int lrow = tid >> 2;
    const int lk   = (tid & 3) * 4;

    float acc[4][4] = {};

    for (int kt = 0; kt < EMB; kt += 16) {
        float4 av = *(const float4*)&A[(size_t)(m0 + lrow) * EMB + kt + lk];
        float4 wv = *(const float4*)&W[(size_t)(n0 + lrow) * EMB + kt + lk];
        As[lk + 0][lrow] = av.x; As[lk + 1][lrow] = av.y;
        As[lk + 2][lrow] = av.z; As[lk + 3][lrow] = av.w;
        Ws[lk + 0][lrow] = wv.x; Ws[lk + 1][lrow] = wv.y;
        Ws[lk + 2][lrow] = wv.z; Ws[lk + 3][lrow] = wv.w;
        __syncthreads();
        #pragma unroll
        for (int kk = 0; kk < 16; ++kk) {
            float4 a = *(const float4*)&As[kk][ty * 4];
            float4 w = *(const float4*)&Ws[kk][tx * 4];
            acc[0][0] += a.x * w.x; acc[0][1] += a.x * w.y;
            acc[0][2] += a.x * w.z; acc[0][3] += a.x * w.w;
            acc[1][0] += a.y * w.x; acc[1][1] += a.y * w.y;
            acc[1][2] += a.y * w.z; acc[1][3] += a.y * w.w;
            acc[2][0] += a.z * w.x; acc[2][1] += a.z * w.y;
            acc[2][2] += a.z * w.z; acc[2][3] += a.z * w.w;
            acc[3][0] += a.w * w.x; acc[3][1] += a.w * w.y;
            acc[3][2] += a.w * w.z; acc[3][3] += a.w * w.w;
        }
        __syncthreads();
    }

    const int n = n0 + tx * 4;
    float bias[4];
    #pragma unroll
    for (int j = 0; j < 4; ++j) bias[j] = b_ih[n + j] + b_hh[n + j];

    #pragma unroll
    for (int i = 0; i < 4; ++i) {
        const int m = m0 + ty * 4 + i;
        const int b = m >> 9;
        const int s = m & 511;
        float4 o;
        o.x = acc[i][0] + bias[0];
        o.y = acc[i][1] + bias[1];
        o.z = acc[i][2] + bias[2];
        o.w = acc[i][3] + bias[3];
        *(float4*)&out[((size_t)(s * 64 + b) << 10) + n] = o;
    }
}

// ---------------------------------------------------------------------------
// 16-lane VALU DPP sum reduction (all 16 lanes end with the group sum).
// ---------------------------------------------------------------------------
__device__ __forceinline__ float red16(float x) {
    int xi, yi;
    xi = __builtin_bit_cast(int, x);
    yi = __builtin_amdgcn_update_dpp(0, xi, 0xB1, 0xF, 0xF, true);  // quad_perm xor1
    x += __builtin_bit_cast(float, yi);
    xi = __builtin_bit_cast(int, x);
    yi = __builtin_amdgcn_update_dpp(0, xi, 0x4E, 0xF, 0xF, true);  // quad_perm xor2
    x += __builtin_bit_cast(float, yi);
    xi = __builtin_bit_cast(int, x);
    yi = __builtin_amdgcn_update_dpp(0, xi, 0x124, 0xF, 0xF, true); // row_ror:4
    x += __builtin_bit_cast(float, yi);
    xi = __builtin_bit_cast(int, x);
    yi = __builtin_amdgcn_update_dpp(0, xi, 0x128, 0xF, 0xF, true); // row_ror:8
    x += __builtin_bit_cast(float, yi);
    return x;
}

// Drain this wave's outstanding VMEM ops. Agent-scope (sc1) atomic stores
// are complete AT THE COHERENCE POINT (LLC) once vmcnt acks — this is the
// release half of the protocol, done per-wave before the barrier.
__device__ __forceinline__ void drain_vmem() {
    asm volatile("s_waitcnt vmcnt(0)" ::: "memory");
}

// ---------------------------------------------------------------------------
// Persistent recurrence kernel: all 512 timesteps in one launch.
// Cross-WG h exchange through the LLC via agent-scope RELAXED atomics
// (per-access cache bypass, NO cache-wide fences -> W_hh/xp stay cached).
// Release protocol per step: every wave issues its h atomic-stores, then
// s_waitcnt vmcnt(0) (stores at LLC), then __syncthreads(), then tid0 bumps
// the flag. Consumer: spin on flag -> barrier -> atomic loads (no spec).
// ---------------------------------------------------------------------------
__global__ __launch_bounds__(512, 2) void rnn_persist(
    const float* __restrict__ Whh,    // HID x HID row-major
    float* __restrict__ out,          // (S, B, HID); xp in, h out (in place)
    int* __restrict__ flags)          // NBG x SEQ counters, pre-zeroed
{
    const int tid  = threadIdx.x;
    const int wave = tid >> 6;
    const int lane = tid & 63;
    const int c    = lane & 15;        // K-chunk index (64 floats per chunk)
    const int jp   = (lane >> 4) & 3;  // j-pair within wave
    const int jt   = blockIdx.x;
    const int bg   = blockIdx.y;
    const int jbase = jt * JTILE + wave * 8 + jp * 2;
    const int k0    = c * 64;

    // --- W_hh slice -> registers (persistent across all steps) ---
    float4 wr0[16], wr1[16];
    #pragma unroll
    for (int kq = 0; kq < 16; ++kq) {
        wr0[kq] = *(const float4*)&Whh[(size_t)jbase * HID + k0 + kq * 4];
        wr1[kq] = *(const float4*)&Whh[(size_t)(jbase + 1) * HID + k0 + kq * 4];
    }

    // h slice LDS: per batch 16 chunks x 68 floats (64 + 4 pad)
    __shared__ float hsf[BTILE * 1088];
    float4* hs4 = (float4*)hsf;

    int* flagrow = flags + bg * SEQ;

    // this lane's output slot (valid when c < 8): b = c>>1, j = jbase + (c&1)
    const int ob = c >> 1;
    const size_t oaddr = (size_t)(bg * BTILE + ob) * HID + (jbase + (c & 1));

    // --- t = 0: h0 = tanh(xp) ---
    if (c < 8) {
        float h0 = tanhf(out[oaddr]);
        __hip_atomic_store(&out[oaddr], h0, __ATOMIC_RELAXED,
                           __HIP_MEMORY_SCOPE_AGENT);
    }
    drain_vmem();          // wave's h0 stores are at the LLC
    __syncthreads();       // all waves drained
    if (tid == 0) {
        __hip_atomic_fetch_add(&flagrow[0], 1, __ATOMIC_RELAXED,
                               __HIP_MEMORY_SCOPE_AGENT);
    }

    // --- t = 1 .. SEQ-1 ---
    for (int t = 1; t < SEQ; ++t) {
        float* cur        = out + (size_t)t * (BATCH * HID);
        const float* prev = cur - (BATCH * HID);

        // prefetch xp (GEMM output; stable across the whole kernel, cached)
        float xp = 0.f;
        if (c < 8) xp = cur[oaddr];

        // wait for all 16 producers of h(t-1) for this batch group
        if (tid == 0) {
            while (__hip_atomic_load(&flagrow[t - 1], __ATOMIC_RELAXED,
                                     __HIP_MEMORY_SCOPE_AGENT) < NJT)
                __builtin_amdgcn_s_sleep(1);
        }
        __syncthreads();

        // fetch h(t-1) slice (4 x 1024 floats) from LLC via 8B agent atomics,
        // stage into LDS. 2048 float2 / 512 threads = 4 per thread.
        #pragma unroll
        for (int q = 0; q < 4; ++q) {
            int f = q * 512 + tid;     // 0..2047
            int b = f >> 9;            // 0..3
            int p = f & 511;           // float2 index within row
            const unsigned long long* rowp =
                (const unsigned long long*)&prev[(size_t)(bg * BTILE + b) * HID];
            unsigned long long v = __hip_atomic_load(
                rowp + p, __ATOMIC_RELAXED, __HIP_MEMORY_SCOPE_AGENT);
            int cc  = p >> 5;          // chunk 0..15
            int off = (p & 31) * 2;    // float offset in chunk
            *(float2*)&hsf[b * 1088 + cc * 68 + off] =
                __builtin_bit_cast(float2, v);
        }
        __syncthreads();

        // compute: acc[b][jj] = partial dot over this lane's 64-k chunk
        float acc[4][2];
        #pragma unroll
        for (int b = 0; b < 4; ++b) {
            const float4* hb = &hs4[b * 272 + c * 17];
            float a0 = 0.f, a1 = 0.f;
            #pragma unroll
            for (int kq = 0; kq < 16; ++kq) {
                float4 h4 = hb[kq];
                a0 += h4.x * wr0[kq].x; a0 += h4.y * wr0[kq].y;
                a0 += h4.z * wr0[kq].z; a0 += h4.w * wr0[kq].w;
                a1 += h4.x * wr1[kq].x; a1 += h4.y * wr1[kq].y;
                a1 += h4.z * wr1[kq].z; a1 += h4.w * wr1[kq].w;
            }
            acc[b][0] = a0; acc[b][1] = a1;
        }

        // K-reduce across the 16 lanes of each jp-group (VALU DPP tree)
        #pragma unroll
        for (int b = 0; b < 4; ++b) {
            acc[b][0] = red16(acc[b][0]);
            acc[b][1] = red16(acc[b][1]);
        }

        // lane c<8 writes output (b = c>>1, jj = c&1) — cndmask select chain
        float vb0 = (c & 1) ? acc[0][1] : acc[0][0];
        float vb1 = (c & 1) ? acc[1][1] : acc[1][0];
        float vb2 = (c & 1) ? acc[2][1] : acc[2][0];
        float vb3 = (c & 1) ? acc[3][1] : acc[3][0];
        float vlo = (c & 2) ? vb1 : vb0;
        float vhi = (c & 2) ? vb3 : vb2;
        float v   = (c & 4) ? vhi : vlo;
        if (c < 8) {
            float hv = tanhf(xp + v);
            __hip_atomic_store(&cur[oaddr], hv, __ATOMIC_RELAXED,
                               __HIP_MEMORY_SCOPE_AGENT);
        }

        drain_vmem();      // THE FIX: wave's h(t) stores are at the LLC
        __syncthreads();   // all waves of this WG drained
        if (tid == 0) {
            __hip_atomic_fetch_add(&flagrow[t], 1, __ATOMIC_RELAXED,
                                   __HIP_MEMORY_SCOPE_AGENT);
        }
    }
}

// ---------------------------------------------------------------------------
extern "C" void kernel_launch(void* const* d_in, const int* in_sizes, int n_in,
                              void* d_out, int out_size, void* d_ws, size_t ws_size,
                              hipStream_t stream) {
    const float* embeds = (const float*)d_in[0];
    const float* W_ih   = (const float*)d_in[1];
    const float* W_hh   = (const float*)d_in[2];
    const float* b_ih   = (const float*)d_in[3];
    const float* b_hh   = (const float*)d_in[4];
    float* out = (float*)d_out;

    (void)in_sizes; (void)n_in; (void)out_size; (void)ws_size;

    // zero the producer flags (graph-captured -> re-zeroed every replay)
    hipMemsetAsync(d_ws, 0, NBG * SEQ * sizeof(int), stream);

    // Phase 1: x_proj for all timesteps, written into d_out at [s][b][:]
    dim3 gA(HID / 64, (BATCH * SEQ) / 64);
    xproj_gemm<<<gA, 256, 0, stream>>>(embeds, W_ih, b_ih, b_hh, out);

    // Phase 2: persistent recurrence (one launch, flag-pipelined)
    dim3 gR(NJT, NBG);
    rnn_persist<<<gR, 512, 0, stream>>>(W_hh, out, (int*)d_ws);
}

// Round 5
// 3602.932 us; speedup vs baseline: 3.0256x; 1.0030x over previous
//
#include <hip/hip_runtime.h>
#include <math.h>

#define EMB   1024
#define HID   1024
#define BATCH   64
#define SEQ    512

#define NBG    16   // batch groups
#define BTILE   4   // batches per group (NBG*BTILE = 64)
#define NJT    16   // j-tiles (producers per batch group)
#define JTILE  64   // j per tile (NJT*JTILE = 1024)

// flags: NBG*NJT slots, each on its own 64B line (16 ints)
#define FLAG_STRIDE 16

// ---------------------------------------------------------------------------
// Kernel A: x_proj GEMM.  out[(s*64+b)*1024 + n] = sum_k embeds[b][s][k]*W_ih[n][k]
//                                                  + b_ih[n] + b_hh[n]
// ---------------------------------------------------------------------------
__global__ __launch_bounds__(256) void xproj_gemm(
    const float* __restrict__ A,
    const float* __restrict__ W,
    const float* __restrict__ b_ih,
    const float* __restrict__ b_hh,
    float* __restrict__ out)
{
    __shared__ float As[16][68];
    __shared__ float Ws[16][68];

    const int tid = threadIdx.x;
    const int tx  = tid & 15;
    const int ty  = tid >> 4;
    const int m0  = blockIdx.y * 64;
    const int n0  = blockIdx.x * 64;
    const int lrow = tid >> 2;
    const int lk   = (tid & 3) * 4;

    float acc[4][4] = {};

    for (int kt = 0; kt < EMB; kt += 16) {
        float4 av = *(const float4*)&A[(size_t)(m0 + lrow) * EMB + kt + lk];
        float4 wv = *(const float4*)&W[(size_t)(n0 + lrow) * EMB + kt + lk];
        As[lk + 0][lrow] = av.x; As[lk + 1][lrow] = av.y;
        As[lk + 2][lrow] = av.z; As[lk + 3][lrow] = av.w;
        Ws[lk + 0][lrow] = wv.x; Ws[lk + 1][lrow] = wv.y;
        Ws[lk + 2][lrow] = wv.z; Ws[lk + 3][lrow] = wv.w;
        __syncthreads();
        #pragma unroll
        for (int kk = 0; kk < 16; ++kk) {
            float4 a = *(const float4*)&As[kk][ty * 4];
            float4 w = *(const float4*)&Ws[kk][tx * 4];
            acc[0][0] += a.x * w.x; acc[0][1] += a.x * w.y;
            acc[0][2] += a.x * w.z; acc[0][3] += a.x * w.w;
            acc[1][0] += a.y * w.x; acc[1][1] += a.y * w.y;
            acc[1][2] += a.y * w.z; acc[1][3] += a.y * w.w;
            acc[2][0] += a.z * w.x; acc[2][1] += a.z * w.y;
            acc[2][2] += a.z * w.z; acc[2][3] += a.z * w.w;
            acc[3][0] += a.w * w.x; acc[3][1] += a.w * w.y;
            acc[3][2] += a.w * w.z; acc[3][3] += a.w * w.w;
        }
        __syncthreads();
    }

    const int n = n0 + tx * 4;
    float bias[4];
    #pragma unroll
    for (int j = 0; j < 4; ++j) bias[j] = b_ih[n + j] + b_hh[n + j];

    #pragma unroll
    for (int i = 0; i < 4; ++i) {
        const int m = m0 + ty * 4 + i;
        const int b = m >> 9;
        const int s = m & 511;
        float4 o;
        o.x = acc[i][0] + bias[0];
        o.y = acc[i][1] + bias[1];
        o.z = acc[i][2] + bias[2];
        o.w = acc[i][3] + bias[3];
        *(float4*)&out[((size_t)(s * 64 + b) << 10) + n] = o;
    }
}

// ---------------------------------------------------------------------------
// 16-lane VALU DPP sum reduction (all 16 lanes end with the group sum).
// ---------------------------------------------------------------------------
__device__ __forceinline__ float red16(float x) {
    int xi, yi;
    xi = __builtin_bit_cast(int, x);
    yi = __builtin_amdgcn_update_dpp(0, xi, 0xB1, 0xF, 0xF, true);  // quad_perm xor1
    x += __builtin_bit_cast(float, yi);
    xi = __builtin_bit_cast(int, x);
    yi = __builtin_amdgcn_update_dpp(0, xi, 0x4E, 0xF, 0xF, true);  // quad_perm xor2
    x += __builtin_bit_cast(float, yi);
    xi = __builtin_bit_cast(int, x);
    yi = __builtin_amdgcn_update_dpp(0, xi, 0x124, 0xF, 0xF, true); // row_ror:4
    x += __builtin_bit_cast(float, yi);
    xi = __builtin_bit_cast(int, x);
    yi = __builtin_amdgcn_update_dpp(0, xi, 0x128, 0xF, 0xF, true); // row_ror:8
    x += __builtin_bit_cast(float, yi);
    return x;
}

// Drain this wave's outstanding VMEM ops. Agent-scope (sc1) atomic stores
// are complete AT THE COHERENCE POINT (LLC) once vmcnt acks.
__device__ __forceinline__ void drain_vmem() {
    asm volatile("s_waitcnt vmcnt(0)" ::: "memory");
}

// ---------------------------------------------------------------------------
// Persistent recurrence kernel: all 512 timesteps in one launch.
// h exchange through the LLC via agent-scope RELAXED atomics (no cache-wide
// fences -> W_hh/xp stay cached in L1/L2).
// Release (per step, per producer WG): h atomic-stores -> vmcnt(0) per wave
// -> s_barrier -> tid0 STORES epoch flag[bg][jt] = t+1 (own 64B line, no RMW).
// Acquire: EVERY wave polls all 16 flags of its bg (lane l loads flag[l&15],
// __all(f>=t)), then immediately issues its h loads; one barrier between LDS
// staging and compute. LDS overwrite is safe because the poll set includes
// the WG's own flag, set only after the release barrier (all waves done
// reading LDS for the previous step).
// ---------------------------------------------------------------------------
__global__ __launch_bounds__(512, 2) void rnn_persist(
    const float* __restrict__ Whh,    // HID x HID row-major
    float* __restrict__ out,          // (S, B, HID); xp in, h out (in place)
    int* __restrict__ flags)          // NBG*NJT slots x 16 ints, pre-zeroed
{
    const int tid  = threadIdx.x;
    const int wave = tid >> 6;
    const int lane = tid & 63;
    const int c    = lane & 15;        // K-chunk index (64 floats per chunk)
    const int jp   = (lane >> 4) & 3;  // j-pair within wave
    const int jt   = blockIdx.x;
    const int bg   = blockIdx.y;
    const int jbase = jt * JTILE + wave * 8 + jp * 2;
    const int k0    = c * 64;

    // --- W_hh slice -> registers (persistent across all steps) ---
    float4 wr0[16], wr1[16];
    #pragma unroll
    for (int kq = 0; kq < 16; ++kq) {
        wr0[kq] = *(const float4*)&Whh[(size_t)jbase * HID + k0 + kq * 4];
        wr1[kq] = *(const float4*)&Whh[(size_t)(jbase + 1) * HID + k0 + kq * 4];
    }

    // h slice LDS: per batch 16 chunks x 68 floats (64 + 4 pad)
    __shared__ float hsf[BTILE * 1088];
    float4* hs4 = (float4*)hsf;

    int* flagbase = flags + bg * NJT * FLAG_STRIDE;  // my bg's 16 producer slots
    int* myflag   = flagbase + jt * FLAG_STRIDE;
    const int pollofs = (lane & 15) * FLAG_STRIDE;   // lane l polls producer l&15

    // this lane's output slot (valid when c < 8): b = c>>1, j = jbase + (c&1)
    const int ob = c >> 1;
    const size_t oaddr = (size_t)(bg * BTILE + ob) * HID + (jbase + (c & 1));

    // --- t = 0: h0 = tanh(xp) ---
    if (c < 8) {
        float h0 = tanhf(out[oaddr]);
        __hip_atomic_store(&out[oaddr], h0, __ATOMIC_RELAXED,
                           __HIP_MEMORY_SCOPE_AGENT);
    }
    drain_vmem();          // wave's h0 stores are at the LLC
    __syncthreads();       // all waves drained (and done with any LDS use)
    if (tid == 0) {
        __hip_atomic_store(myflag, 1, __ATOMIC_RELAXED,
                           __HIP_MEMORY_SCOPE_AGENT);
    }

    // --- t = 1 .. SEQ-1 ---
    for (int t = 1; t < SEQ; ++t) {
        float* cur        = out + (size_t)t * (BATCH * HID);
        const float* prev = cur - (BATCH * HID);

        // prefetch xp (GEMM output; only this WG ever touches this slot)
        float xp = 0.f;
        if (c < 8) xp = cur[oaddr];

        // acquire: wait until all 16 producers of h(t-1) have released
        for (;;) {
            int f = __hip_atomic_load(flagbase + pollofs, __ATOMIC_RELAXED,
                                      __HIP_MEMORY_SCOPE_AGENT);
            if (__all(f >= t)) break;
            __builtin_amdgcn_s_sleep(1);
        }

        // fetch h(t-1) slice (4 x 1024 floats) from LLC via 8B agent atomics,
        // stage into LDS. 2048 float2 / 512 threads = 4 per thread.
        #pragma unroll
        for (int q = 0; q < 4; ++q) {
            int f = q * 512 + tid;     // 0..2047
            int b = f >> 9;            // 0..3
            int p = f & 511;           // float2 index within row
            const unsigned long long* rowp =
                (const unsigned long long*)&prev[(size_t)(bg * BTILE + b) * HID];
            unsigned long long v = __hip_atomic_load(
                rowp + p, __ATOMIC_RELAXED, __HIP_MEMORY_SCOPE_AGENT);
            int cc  = p >> 5;          // chunk 0..15
            int off = (p & 31) * 2;    // float offset in chunk
            *(float2*)&hsf[b * 1088 + cc * 68 + off] =
                __builtin_bit_cast(float2, v);
        }
        __syncthreads();   // staging complete across all 8 waves

        // compute: acc[b][jj] = partial dot over this lane's 64-k chunk
        float acc[4][2];
        #pragma unroll
        for (int b = 0; b < 4; ++b) {
            const float4* hb = &hs4[b * 272 + c * 17];
            float a0 = 0.f, a1 = 0.f;
            #pragma unroll
            for (int kq = 0; kq < 16; ++kq) {
                float4 h4 = hb[kq];
                a0 += h4.x * wr0[kq].x; a0 += h4.y * wr0[kq].y;
                a0 += h4.z * wr0[kq].z; a0 += h4.w * wr0[kq].w;
                a1 += h4.x * wr1[kq].x; a1 += h4.y * wr1[kq].y;
                a1 += h4.z * wr1[kq].z; a1 += h4.w * wr1[kq].w;
            }
            acc[b][0] = a0; acc[b][1] = a1;
        }

        // K-reduce across the 16 lanes of each jp-group (VALU DPP tree)
        #pragma unroll
        for (int b = 0; b < 4; ++b) {
            acc[b][0] = red16(acc[b][0]);
            acc[b][1] = red16(acc[b][1]);
        }

        // lane c<8 writes output (b = c>>1, jj = c&1) — cndmask select chain
        float vb0 = (c & 1) ? acc[0][1] : acc[0][0];
        float vb1 = (c & 1) ? acc[1][1] : acc[1][0];
        float vb2 = (c & 1) ? acc[2][1] : acc[2][0];
        float vb3 = (c & 1) ? acc[3][1] : acc[3][0];
        float vlo = (c & 2) ? vb1 : vb0;
        float vhi = (c & 2) ? vb3 : vb2;
        float v   = (c & 4) ? vhi : vlo;
        if (c < 8) {
            float hv = tanhf(xp + v);
            __hip_atomic_store(&cur[oaddr], hv, __ATOMIC_RELAXED,
                               __HIP_MEMORY_SCOPE_AGENT);
        }

        drain_vmem();      // wave's h(t) stores are at the LLC
        __syncthreads();   // all waves drained AND done reading hs for step t
        if (tid == 0) {
            __hip_atomic_store(myflag, t + 1, __ATOMIC_RELAXED,
                               __HIP_MEMORY_SCOPE_AGENT);
        }
    }
}

// ---------------------------------------------------------------------------
extern "C" void kernel_launch(void* const* d_in, const int* in_sizes, int n_in,
                              void* d_out, int out_size, void* d_ws, size_t ws_size,
                              hipStream_t stream) {
    const float* embeds = (const float*)d_in[0];
    const float* W_ih   = (const float*)d_in[1];
    const float* W_hh   = (const float*)d_in[2];
    const float* b_ih   = (const float*)d_in[3];
    const float* b_hh   = (const float*)d_in[4];
    float* out = (float*)d_out;

    (void)in_sizes; (void)n_in; (void)out_size; (void)ws_size;

    // zero the epoch flags (graph-captured -> re-zeroed every replay)
    hipMemsetAsync(d_ws, 0, NBG * NJT * FLAG_STRIDE * sizeof(int), stream);

    // Phase 1: x_proj for all timesteps, written into d_out at [s][b][:]
    dim3 gA(HID / 64, (BATCH * SEQ) / 64);
    xproj_gemm<<<gA, 256, 0, stream>>>(embeds, W_ih, b_ih, b_hh, out);

    // Phase 2: persistent recurrence (one launch, flag-pipelined)
    dim3 gR(NJT, NBG);
    rnn_persist<<<gR, 512, 0, stream>>>(W_hh, out, (int*)d_ws);
}

// Round 6
// 3139.189 us; speedup vs baseline: 3.4725x; 1.1477x over previous
//
#include <hip/hip_runtime.h>
#include <math.h>

#define EMB   1024
#define HID   1024
#define BATCH   64
#define SEQ    512

#define NBG    16   // batch groups
#define BTILE   4   // batches per group (NBG*BTILE = 64)
#define NJT    16   // j-tiles (producers per batch group)
#define JTILE  64   // j per tile (NJT*JTILE = 1024)

#define FLAG_STRIDE 16   // one 64B line per producer flag

typedef float f32x4 __attribute__((ext_vector_type(4)));

// ---------------------------------------------------------------------------
// Kernel A: x_proj GEMM.  out[(s*64+b)*1024 + n] = sum_k embeds[b][s][k]*W_ih[n][k]
//                                                  + b_ih[n] + b_hh[n]
// ---------------------------------------------------------------------------
__global__ __launch_bounds__(256) void xproj_gemm(
    const float* __restrict__ A,
    const float* __restrict__ W,
    const float* __restrict__ b_ih,
    const float* __restrict__ b_hh,
    float* __restrict__ out)
{
    __shared__ float As[16][68];
    __shared__ float Ws[16][68];

    const int tid = threadIdx.x;
    const int tx  = tid & 15;
    const int ty  = tid >> 4;
    const int m0  = blockIdx.y * 64;
    const int n0  = blockIdx.x * 64;
    const int lrow = tid >> 2;
    const int lk   = (tid & 3) * 4;

    float acc[4][4] = {};

    for (int kt = 0; kt < EMB; kt += 16) {
        float4 av = *(const float4*)&A[(size_t)(m0 + lrow) * EMB + kt + lk];
        float4 wv = *(const float4*)&W[(size_t)(n0 + lrow) * EMB + kt + lk];
        As[lk + 0][lrow] = av.x; As[lk + 1][lrow] = av.y;
        As[lk + 2][lrow] = av.z; As[lk + 3][lrow] = av.w;
        Ws[lk + 0][lrow] = wv.x; Ws[lk + 1][lrow] = wv.y;
        Ws[lk + 2][lrow] = wv.z; Ws[lk + 3][lrow] = wv.w;
        __syncthreads();
        #pragma unroll
        for (int kk = 0; kk < 16; ++kk) {
            float4 a = *(const float4*)&As[kk][ty * 4];
            float4 w = *(const float4*)&Ws[kk][tx * 4];
            acc[0][0] += a.x * w.x; acc[0][1] += a.x * w.y;
            acc[0][2] += a.x * w.z; acc[0][3] += a.x * w.w;
            acc[1][0] += a.y * w.x; acc[1][1] += a.y * w.y;
            acc[1][2] += a.y * w.z; acc[1][3] += a.y * w.w;
            acc[2][0] += a.z * w.x; acc[2][1] += a.z * w.y;
            acc[2][2] += a.z * w.z; acc[2][3] += a.z * w.w;
            acc[3][0] += a.w * w.x; acc[3][1] += a.w * w.y;
            acc[3][2] += a.w * w.z; acc[3][3] += a.w * w.w;
        }
        __syncthreads();
    }

    const int n = n0 + tx * 4;
    float bias[4];
    #pragma unroll
    for (int j = 0; j < 4; ++j) bias[j] = b_ih[n + j] + b_hh[n + j];

    #pragma unroll
    for (int i = 0; i < 4; ++i) {
        const int m = m0 + ty * 4 + i;
        const int b = m >> 9;
        const int s = m & 511;
        float4 o;
        o.x = acc[i][0] + bias[0];
        o.y = acc[i][1] + bias[1];
        o.z = acc[i][2] + bias[2];
        o.w = acc[i][3] + bias[3];
        *(float4*)&out[((size_t)(s * 64 + b) << 10) + n] = o;
    }
}

// ---------------------------------------------------------------------------
// 16-lane VALU DPP sum reduction (all 16 lanes end with the group sum).
// ---------------------------------------------------------------------------
__device__ __forceinline__ float red16(float x) {
    int xi, yi;
    xi = __builtin_bit_cast(int, x);
    yi = __builtin_amdgcn_update_dpp(0, xi, 0xB1, 0xF, 0xF, true);  // quad_perm xor1
    x += __builtin_bit_cast(float, yi);
    xi = __builtin_bit_cast(int, x);
    yi = __builtin_amdgcn_update_dpp(0, xi, 0x4E, 0xF, 0xF, true);  // quad_perm xor2
    x += __builtin_bit_cast(float, yi);
    xi = __builtin_bit_cast(int, x);
    yi = __builtin_amdgcn_update_dpp(0, xi, 0x124, 0xF, 0xF, true); // row_ror:4
    x += __builtin_bit_cast(float, yi);
    xi = __builtin_bit_cast(int, x);
    yi = __builtin_amdgcn_update_dpp(0, xi, 0x128, 0xF, 0xF, true); // row_ror:8
    x += __builtin_bit_cast(float, yi);
    return x;
}

__device__ __forceinline__ void drain_vmem() {
    asm volatile("s_waitcnt vmcnt(0)" ::: "memory");
}

// 16B coherent load from the LLC (sc1 -> serviced at the device coherence
// point, never from a stale L1/L2 line). Atomicity within the 16B is NOT
// needed: data is stable by the time we read (flag acquire happened-before).
__device__ __forceinline__ f32x4 llc_load4(const float* p) {
    f32x4 v;
    asm volatile("global_load_dwordx4 %0, %1, off sc1"
                 : "=v"(v) : "v"(p) : "memory");
    return v;
}

// ---------------------------------------------------------------------------
// Persistent recurrence kernel: all 512 timesteps in one launch.
// h exchange through the LLC via sc1 accesses (no cache-wide fences ->
// W_hh/xp stay cached). Release: h sc1-stores -> vmcnt(0)/wave -> s_barrier
// -> tid0 stores epoch flag (own 64B line). Acquire: every wave polls all
// 16 producer flags of its bg, then issues 16B sc1 h loads.
// W_hh slice is PINNED in VGPRs via opaque asm redefinition (without it the
// compiler rematerializes the W loads into the t-loop and streams 256 KB
// from L2 every step — observed as VGPR_Count=80 in rounds 2-5).
// ---------------------------------------------------------------------------
__global__ __launch_bounds__(512, 2) void rnn_persist(
    const float* __restrict__ Whh,    // HID x HID row-major
    float* __restrict__ out,          // (S, B, HID); xp in, h out (in place)
    int* __restrict__ flags)          // NBG*NJT slots x 16 ints, pre-zeroed
{
    const int tid  = threadIdx.x;
    const int wave = tid >> 6;
    const int lane = tid & 63;
    const int c    = lane & 15;        // K-chunk index (64 floats per chunk)
    const int jp   = (lane >> 4) & 3;  // j-pair within wave
    const int jt   = blockIdx.x;
    const int bg   = blockIdx.y;
    const int jbase = jt * JTILE + wave * 8 + jp * 2;
    const int k0    = c * 64;

    // --- W_hh slice -> VGPRs, pinned (persistent across all steps) ---
    f32x4 wr0[16], wr1[16];
    #pragma unroll
    for (int kq = 0; kq < 16; ++kq) {
        wr0[kq] = *(const f32x4*)&Whh[(size_t)jbase * HID + k0 + kq * 4];
        wr1[kq] = *(const f32x4*)&Whh[(size_t)(jbase + 1) * HID + k0 + kq * 4];
    }
    #pragma unroll
    for (int kq = 0; kq < 16; ++kq) {
        asm volatile("" : "+v"(wr0[kq]));   // opaque redefinition: the value
        asm volatile("" : "+v"(wr1[kq]));   // can no longer be remat'd as a load
    }

    // h slice LDS: per batch 16 chunks x 68 floats (64 + 4 pad)
    __shared__ float hsf[BTILE * 1088];

    int* flagbase = flags + bg * NJT * FLAG_STRIDE;
    int* myflag   = flagbase + jt * FLAG_STRIDE;
    const int pollofs = (lane & 15) * FLAG_STRIDE;

    // this lane's output slot (valid when c < 8): b = c>>1, j = jbase + (c&1)
    const int ob = c >> 1;
    const size_t oaddr = (size_t)(bg * BTILE + ob) * HID + (jbase + (c & 1));

    // h-load assignment: thread handles float4 indices tid and tid+512 of the
    // 1024-float4 (4 x 1024 floats) bg slice.
    const int p0 = tid, p1 = tid + 512;
    const int b0i = p0 >> 8, r0 = p0 & 255;
    const int b1i = p1 >> 8, r1 = p1 & 255;
    const size_t goff0 = (size_t)(bg * BTILE + b0i) * HID + r0 * 4;
    const size_t goff1 = (size_t)(bg * BTILE + b1i) * HID + r1 * 4;
    const int loff0 = b0i * 1088 + (r0 >> 4) * 68 + (r0 & 15) * 4;
    const int loff1 = b1i * 1088 + (r1 >> 4) * 68 + (r1 & 15) * 4;

    // --- t = 0: h0 = tanh(xp) ---
    if (c < 8) {
        float h0 = tanhf(out[oaddr]);
        __hip_atomic_store(&out[oaddr], h0, __ATOMIC_RELAXED,
                           __HIP_MEMORY_SCOPE_AGENT);
    }
    drain_vmem();
    __syncthreads();
    if (tid == 0) {
        __hip_atomic_store(myflag, 1, __ATOMIC_RELAXED,
                           __HIP_MEMORY_SCOPE_AGENT);
    }

    // --- t = 1 .. SEQ-1 ---
    for (int t = 1; t < SEQ; ++t) {
        float* cur        = out + (size_t)t * (BATCH * HID);
        const float* prev = cur - (BATCH * HID);

        // prefetch xp (GEMM output; only this WG ever touches this slot)
        float xp = 0.f;
        if (c < 8) xp = cur[oaddr];

        // acquire: wait until all 16 producers of h(t-1) have released
        for (;;) {
            int f = __hip_atomic_load(flagbase + pollofs, __ATOMIC_RELAXED,
                                      __HIP_MEMORY_SCOPE_AGENT);
            if (__all(f >= t)) break;
            __builtin_amdgcn_s_sleep(1);
        }

        // fetch h(t-1) slice: 2 x 16B sc1 loads per thread -> LDS
        f32x4 hv0 = llc_load4(prev + goff0);
        f32x4 hv1 = llc_load4(prev + goff1);
        drain_vmem();                       // loads complete before LDS write
        *(f32x4*)&hsf[loff0] = hv0;
        *(f32x4*)&hsf[loff1] = hv1;
        __builtin_amdgcn_sched_barrier(0);
        __syncthreads();

        // compute: acc[b][jj] = partial dot over this lane's 64-k chunk
        float acc[4][2];
        #pragma unroll
        for (int b = 0; b < 4; ++b) {
            const f32x4* hb = (const f32x4*)&hsf[b * 1088 + c * 68];
            f32x4 a0 = {0.f, 0.f, 0.f, 0.f};
            f32x4 a1 = {0.f, 0.f, 0.f, 0.f};
            #pragma unroll
            for (int kq = 0; kq < 16; ++kq) {
                f32x4 h4 = hb[kq];
                a0 += h4 * wr0[kq];
                a1 += h4 * wr1[kq];
            }
            acc[b][0] = (a0.x + a0.y) + (a0.z + a0.w);
            acc[b][1] = (a1.x + a1.y) + (a1.z + a1.w);
        }

        // K-reduce across the 16 lanes of each jp-group (VALU DPP tree)
        #pragma unroll
        for (int b = 0; b < 4; ++b) {
            acc[b][0] = red16(acc[b][0]);
            acc[b][1] = red16(acc[b][1]);
        }

        // lane c<8 writes output (b = c>>1, jj = c&1)
        float vb0 = (c & 1) ? acc[0][1] : acc[0][0];
        float vb1 = (c & 1) ? acc[1][1] : acc[1][0];
        float vb2 = (c & 1) ? acc[2][1] : acc[2][0];
        float vb3 = (c & 1) ? acc[3][1] : acc[3][0];
        float vlo = (c & 2) ? vb1 : vb0;
        float vhi = (c & 2) ? vb3 : vb2;
        float v   = (c & 4) ? vhi : vlo;
        if (c < 8) {
            float hv = tanhf(xp + v);
            __hip_atomic_store(&cur[oaddr], hv, __ATOMIC_RELAXED,
                               __HIP_MEMORY_SCOPE_AGENT);
        }

        drain_vmem();      // wave's h(t) stores are at the LLC
        __syncthreads();   // all waves drained AND done reading hs for step t
        if (tid == 0) {
            __hip_atomic_store(myflag, t + 1, __ATOMIC_RELAXED,
                               __HIP_MEMORY_SCOPE_AGENT);
        }
    }
}

// ---------------------------------------------------------------------------
extern "C" void kernel_launch(void* const* d_in, const int* in_sizes, int n_in,
                              void* d_out, int out_size, void* d_ws, size_t ws_size,
                              hipStream_t stream) {
    const float* embeds = (const float*)d_in[0];
    const float* W_ih   = (const float*)d_in[1];
    const float* W_hh   = (const float*)d_in[2];
    const float* b_ih   = (const float*)d_in[3];
    const float* b_hh   = (const float*)d_in[4];
    float* out = (float*)d_out;

    (void)in_sizes; (void)n_in; (void)out_size; (void)ws_size;

    // zero the epoch flags (graph-captured -> re-zeroed every replay)
    hipMemsetAsync(d_ws, 0, NBG * NJT * FLAG_STRIDE * sizeof(int), stream);

    // Phase 1: x_proj for all timesteps, written into d_out at [s][b][:]
    dim3 gA(HID / 64, (BATCH * SEQ) / 64);
    xproj_gemm<<<gA, 256, 0, stream>>>(embeds, W_ih, b_ih, b_hh, out);

    // Phase 2: persistent recurrence (one launch, flag-pipelined)
    dim3 gR(NJT, NBG);
    rnn_persist<<<gR, 512, 0, stream>>>(W_hh, out, (int*)d_ws);
}